// Round 1
// baseline (101.173 us; speedup 1.0000x reference)
//
#include <hip/hip_runtime.h>
#include <math.h>

#define BB 16
#define LL 2048
#define DD 256
#define NPOS 126
#define NSEG 127            // chunk_counts bins = NPOS + 1
#define MS 1152             // max segments per utterance
#define POS_MAX (24 + 16 * (NPOS - 1))   // 2024

// ws layout (floats/ints):
//   w        : BB*LL floats            @ byte 0
//   starts   : BB*MS ints              @ byte BB*LL*4
//   counts_i : BB ints                 @ byte BB*LL*4 + BB*MS*4

// ---------------- Kernel 1: w[b,t] = sigmoid(x[b,t,:] . w_lin + b_lin) -------
// one wave per row; 64 lanes x float4 = 256 dims
__global__ __launch_bounds__(256) void k_proj(const float* __restrict__ xs,
                                              const float* __restrict__ w_lin,
                                              const float* __restrict__ b_lin,
                                              float* __restrict__ w) {
    int gtid = blockIdx.x * 256 + threadIdx.x;
    int row  = gtid >> 6;          // wave id == row, grid sized exactly
    int lane = threadIdx.x & 63;
    const float4 x4 = *(const float4*)(xs + (size_t)row * DD + lane * 4);
    const float4 wl = *(const float4*)(w_lin + lane * 4);
    float p = x4.x * wl.x + x4.y * wl.y + x4.z * wl.z + x4.w * wl.w;
    #pragma unroll
    for (int off = 32; off > 0; off >>= 1) p += __shfl_down(p, off, 64);
    if (lane == 0) {
        float x = p + b_lin[0];
        // stable sigmoid, matching jax.nn.sigmoid formulation
        float s = (x >= 0.f) ? 1.f / (1.f + expf(-x))
                             : expf(x) / (1.f + expf(x));
        w[row] = s;
    }
}

// ---------------- Kernel 2: mask -> starts/counts/chunk_counts ---------------
// one block (256 threads) per batch item; each thread owns 8 consecutive t
__global__ __launch_bounds__(256) void k_mask(const float* __restrict__ w,
                                              int* __restrict__ starts,
                                              int* __restrict__ counts_i,
                                              float* __restrict__ out_counts,
                                              float* __restrict__ out_cc) {
    int b   = blockIdx.x;
    int tid = threadIdx.x;
    __shared__ float sw[LL];
    __shared__ int   scc[NSEG];
    __shared__ int   wave_tot[4];

    for (int i = tid; i < LL; i += 256) sw[i] = w[b * LL + i];
    for (int i = tid; i < NSEG; i += 256) scc[i] = 0;
    __syncthreads();

    int base_t = tid * 8;
    bool bits[8];
    int c = 0;
    #pragma unroll
    for (int j = 0; j < 8; ++j) {
        int t = base_t + j;
        float wd = sw[t];
        float pv = (t > 0)      ? sw[t - 1] : 0.f;   // F.pad-style zero pads
        float nx = (t < LL - 1) ? sw[t + 1] : 0.f;
        bool m = (wd < pv) && (wd < nx);             // strict local minimum
        if (t == 0) m = true;                        // forced index 0
        if (t >= 24 && t <= POS_MAX && ((t - 24) & 15) == 0) m = true; // chunks
        bits[j] = m;
        c += m ? 1 : 0;
    }

    // block exclusive scan of per-thread counts (4 waves of 64)
    int lane = tid & 63, wv = tid >> 6;
    int inc = c;
    #pragma unroll
    for (int off = 1; off < 64; off <<= 1) {
        int v = __shfl_up(inc, off, 64);
        if (lane >= off) inc += v;
    }
    if (lane == 63) wave_tot[wv] = inc;
    __syncthreads();
    int wbase = 0;
    for (int i = 0; i < wv; ++i) wbase += wave_tot[i];
    int total = wave_tot[0] + wave_tot[1] + wave_tot[2] + wave_tot[3];
    int rank  = wbase + inc - c;   // exclusive prefix for this thread

    #pragma unroll
    for (int j = 0; j < 8; ++j) {
        if (bits[j]) {
            int t = base_t + j;
            starts[b * MS + rank] = t;
            ++rank;
            int sid = (t < 24) ? 0 : min((t - 24) / 16 + 1, NSEG - 1);
            atomicAdd(&scc[sid], 1);
        }
    }
    if (tid == 0) { counts_i[b] = total; out_counts[b] = (float)total; }
    __syncthreads();   // scc atomics done; total visible
    for (int i = total + tid; i < MS; i += 256) starts[b * MS + i] = LL;
    for (int i = tid; i < NSEG; i += 256) out_cc[b * NSEG + i] = (float)scc[i];
}

// ---------------- Kernel 3: per-segment weighted mean + LayerNorm ------------
// one wave per (b,k) segment slot
__global__ __launch_bounds__(256) void k_segs(const float* __restrict__ xs,
                                              const float* __restrict__ w,
                                              const int* __restrict__ starts,
                                              const int* __restrict__ counts_i,
                                              const float* __restrict__ gamma,
                                              const float* __restrict__ beta,
                                              float* __restrict__ out) {
    int gtid = blockIdx.x * 256 + threadIdx.x;
    int seg  = gtid >> 6;          // exact grid: BB*MS waves
    int lane = threadIdx.x & 63;
    int b = seg / MS, k = seg - b * MS;
    int cnt = counts_i[b];
    float* orow = out + (size_t)seg * DD + lane * 4;
    if (k >= cnt) {                // padded slot: start==end==L -> zeros after LN
        *(float4*)orow = make_float4(0.f, 0.f, 0.f, 0.f);
        return;
    }
    int start = starts[b * MS + k];
    int end   = (k + 1 < cnt) ? min(starts[b * MS + k + 1] + 2, LL) : LL;

    float4 acc = make_float4(0.f, 0.f, 0.f, 0.f);
    float den = 0.f;
    const float* xrow = xs + ((size_t)(b * LL + start)) * DD + lane * 4;
    for (int t = start; t < end; ++t, xrow += DD) {
        float wt = w[b * LL + t];
        float4 x4 = *(const float4*)xrow;
        acc.x += wt * x4.x; acc.y += wt * x4.y;
        acc.z += wt * x4.z; acc.w += wt * x4.w;
        den += wt;
    }
    float inv = 1.f / fmaxf(den, 1e-6f);
    float4 v = make_float4(acc.x * inv, acc.y * inv, acc.z * inv, acc.w * inv);

    // mean
    float s = v.x + v.y + v.z + v.w;
    #pragma unroll
    for (int off = 32; off > 0; off >>= 1) s += __shfl_down(s, off, 64);
    s = __shfl(s, 0, 64);
    float mu = s * (1.f / DD);
    // two-pass variance (matches reference mean((x-mu)^2))
    float dx = v.x - mu, dy = v.y - mu, dz = v.z - mu, dw = v.w - mu;
    float q = dx * dx + dy * dy + dz * dz + dw * dw;
    #pragma unroll
    for (int off = 32; off > 0; off >>= 1) q += __shfl_down(q, off, 64);
    q = __shfl(q, 0, 64);
    float rstd = rsqrtf(q * (1.f / DD) + 1e-5f);

    float4 g  = *(const float4*)(gamma + lane * 4);
    float4 bt = *(const float4*)(beta + lane * 4);
    float4 o;
    o.x = dx * rstd * g.x + bt.x;
    o.y = dy * rstd * g.y + bt.y;
    o.z = dz * rstd * g.z + bt.z;
    o.w = dw * rstd * g.w + bt.w;
    *(float4*)orow = o;
}

extern "C" void kernel_launch(void* const* d_in, const int* in_sizes, int n_in,
                              void* d_out, int out_size, void* d_ws, size_t ws_size,
                              hipStream_t stream) {
    const float* xs    = (const float*)d_in[0];
    // d_in[1] = olens (unused by reference math)
    const float* w_lin = (const float*)d_in[2];
    const float* b_lin = (const float*)d_in[3];
    const float* gamma = (const float*)d_in[4];
    const float* beta  = (const float*)d_in[5];

    float* out       = (float*)d_out;                       // [B,MS,D]
    float* out_cnt   = out + (size_t)BB * MS * DD;          // [B] as f32
    float* out_cc    = out_cnt + BB;                        // [B,NSEG] as f32

    float* w         = (float*)d_ws;                        // [B,L]
    int*   starts    = (int*)((char*)d_ws + (size_t)BB * LL * 4);
    int*   counts_i  = (int*)((char*)d_ws + (size_t)BB * LL * 4 + (size_t)BB * MS * 4);

    // K1: BB*LL rows, 1 wave each, 4 waves/block
    k_proj<<<(BB * LL) / 4, 256, 0, stream>>>(xs, w_lin, b_lin, w);
    // K2: one block per batch
    k_mask<<<BB, 256, 0, stream>>>(w, starts, counts_i, out_cnt, out_cc);
    // K3: BB*MS segment slots, 1 wave each, 4 waves/block
    k_segs<<<(BB * MS) / 4, 256, 0, stream>>>(xs, w, starts, counts_i,
                                              gamma, beta, out);
}